// Round 7
// baseline (195.242 us; speedup 1.0000x reference)
//
#include <hip/hip_runtime.h>
#include <math.h>

#define HIDDEN 4096
#define NEXP 64
#define TOPK 8
#define MARGIN 2.5e-4f
#define BK 64
#define TPB 32            // tokens per block
#define NCHUNK (HIDDEN / BK)

using short8   = __attribute__((ext_vector_type(8))) short;   // 8 bf16 fragment
using floatx4  = __attribute__((ext_vector_type(4))) float;   // MFMA acc
using ushort4v = __attribute__((ext_vector_type(4))) unsigned short;

// d_ws layout: [0,4) redo counter | [64, 64+64K) redo token list |
//              [128K, 640K) W_hi bf16[64][4096] | [640K, 1152K) W_lo
#define WS_LIST_OFF (64)
#define WS_WHI_OFF  (128 * 1024)
#define WS_WLO_OFF  (640 * 1024)
#define WS_NEED     (1152 * 1024)

__device__ __forceinline__ unsigned short bf16_rn(float x) {
    unsigned int u = __builtin_bit_cast(unsigned int, x);
    unsigned int r = u + 0x7FFFu + ((u >> 16) & 1u);   // round-to-nearest-even
    return (unsigned short)(r >> 16);
}
__device__ __forceinline__ float bf16_to_f(unsigned short h) {
    unsigned int u = ((unsigned int)h) << 16;
    return __builtin_bit_cast(float, u);
}

__device__ __forceinline__ void gload16(const void* g, void* l) {
    __builtin_amdgcn_global_load_lds(
        (const __attribute__((address_space(1))) void*)g,
        (__attribute__((address_space(3))) void*)l, 16, 0, 0);
}

// ---------------- pass 0: split W into bf16 hi/lo (RN, runs every call) ----
__global__ void wconv_kernel(const float* __restrict__ W,
                             unsigned short* __restrict__ Whi,
                             unsigned short* __restrict__ Wlo,
                             int* __restrict__ cnt) {
    if (blockIdx.x == 0 && threadIdx.x == 0) *cnt = 0;
    int i = (blockIdx.x * 256 + threadIdx.x) * 4;
    float4 w = *reinterpret_cast<const float4*>(W + i);
    float ws4[4] = {w.x, w.y, w.z, w.w};
    unsigned short h[4], l[4];
#pragma unroll
    for (int j = 0; j < 4; ++j) {
        h[j] = bf16_rn(ws4[j]);
        l[j] = bf16_rn(ws4[j] - bf16_to_f(h[j]));
    }
    ushort4v hv = {h[0], h[1], h[2], h[3]};
    ushort4v lv = {l[0], l[1], l[2], l[3]};
    *reinterpret_cast<ushort4v*>(Whi + i) = hv;
    *reinterpret_cast<ushort4v*>(Wlo + i) = lv;
}

// ---------------- pass 1: MFMA gate, triple-buffered counted-vmcnt ---------
// 512 thr = 8 waves; block owns 32 tokens x 64 experts.
// Wave q: token-tile tt=q>>2 (16 tokens), expert-tile et=q&3 (16 experts).
// LDS: 3 buffer sets x {X [32][64] f32 8KB | Whi [64][64] bf16 8KB | Wlo 8KB}.
// Swizzle both sides (rule #21): byte ^= (row&7)<<4.
// Pipeline: stage(c) waited with vmcnt(3) (stage(c+1) stays in flight across
// the barrier); stage(c+2) issued right after the barrier. Never drain to 0.

__global__ __launch_bounds__(512, 4)
void gate_mfma(const float* __restrict__ X,
               const unsigned short* __restrict__ Whi,
               const unsigned short* __restrict__ Wlo,
               float* __restrict__ out,
               int* __restrict__ redo_cnt, int* __restrict__ redo_list, int T) {
    __shared__ __align__(16) char smem[73728];   // 3 x 24 KB
    const int tid  = threadIdx.x;
    const int lane = tid & 63;
    const int q    = tid >> 6;              // 0..7
    const int tt   = q >> 2;                // 0..1
    const int et   = q & 3;                 // 0..3
    const int t0   = blockIdx.x * TPB;

    // --- staging: wave q issues slots 3q..3q+2 (24 gload_lds per chunk) ---
    auto stage = [&](int buf, int kb) {     // kb in elements
        char* base = smem + buf * 24576;
#pragma unroll
        for (int j = 0; j < 3; ++j) {
            const int s = q * 3 + j;
            if (s < 8) {                    // X rows 4s..4s+3
                const int r  = s * 4 + (lane >> 4);
                const int cb = (lane & 15) * 16;
                const int sw = cb ^ ((r & 7) << 4);
                gload16(X + (size_t)(t0 + r) * HIDDEN + kb + (sw >> 2),
                        base + s * 1024);
            } else if (s < 16) {            // Whi rows 8i..8i+7
                const int i  = s - 8;
                const int r  = i * 8 + (lane >> 3);
                const int cb = (lane & 7) * 16;
                const int sw = cb ^ ((r & 7) << 4);
                gload16(Whi + (size_t)r * HIDDEN + kb + (sw >> 1),
                        base + 8192 + i * 1024);
            } else {                        // Wlo rows
                const int i  = s - 16;
                const int r  = i * 8 + (lane >> 3);
                const int cb = (lane & 7) * 16;
                const int sw = cb ^ ((r & 7) << 4);
                gload16(Wlo + (size_t)r * HIDDEN + kb + (sw >> 1),
                        base + 16384 + i * 1024);
            }
        }
    };

    floatx4 acc = {0.f, 0.f, 0.f, 0.f};
    const int arow = tt * 16 + (lane & 15);       // LDS X row
    const int brow = et * 16 + (lane & 15);       // LDS W row
    const int asz  = (arow & 7) << 4;
    const int bsz  = (brow & 7) << 4;

    auto compute = [&](int buf) {
        const char* xb = smem + buf * 24576;
        const char* hb = xb + 8192;
        const char* lb = xb + 16384;
#pragma unroll
        for (int ks = 0; ks < 2; ++ks) {
            const int ab0 = ks * 128 + (lane >> 4) * 32;
            const float4 xa = *reinterpret_cast<const float4*>(xb + arow * 256 + ((ab0     ) ^ asz));
            const float4 xc = *reinterpret_cast<const float4*>(xb + arow * 256 + ((ab0 + 16) ^ asz));
            const int bb0 = ks * 64 + (lane >> 4) * 16;
            const short8 bh = *reinterpret_cast<const short8*>(hb + brow * 128 + (bb0 ^ bsz));
            const short8 bl = *reinterpret_cast<const short8*>(lb + brow * 128 + (bb0 ^ bsz));
            // bf16 hi/lo truncation split, v_perm-packed (2 elems/inst)
            unsigned int xu[8] = {
                __builtin_bit_cast(unsigned int, xa.x), __builtin_bit_cast(unsigned int, xa.y),
                __builtin_bit_cast(unsigned int, xa.z), __builtin_bit_cast(unsigned int, xa.w),
                __builtin_bit_cast(unsigned int, xc.x), __builtin_bit_cast(unsigned int, xc.y),
                __builtin_bit_cast(unsigned int, xc.z), __builtin_bit_cast(unsigned int, xc.w)};
            unsigned int hw[4], lw[4];
#pragma unroll
            for (int p = 0; p < 4; ++p) {
                unsigned int u0 = xu[2 * p], u1 = xu[2 * p + 1];
                hw[p] = __builtin_amdgcn_perm(u1, u0, 0x07060302u);  // hi16(u1):hi16(u0)
                float d0 = __builtin_bit_cast(float, xu[2 * p])     - __builtin_bit_cast(float, u0 & 0xFFFF0000u);
                float d1 = __builtin_bit_cast(float, xu[2 * p + 1]) - __builtin_bit_cast(float, u1 & 0xFFFF0000u);
                lw[p] = __builtin_amdgcn_perm(__builtin_bit_cast(unsigned int, d1),
                                              __builtin_bit_cast(unsigned int, d0), 0x07060302u);
            }
            using uint4v = __attribute__((ext_vector_type(4))) unsigned int;
            uint4v hv = {hw[0], hw[1], hw[2], hw[3]};
            uint4v lv = {lw[0], lw[1], lw[2], lw[3]};
            short8 ah = __builtin_bit_cast(short8, hv);
            short8 al = __builtin_bit_cast(short8, lv);
            acc = __builtin_amdgcn_mfma_f32_16x16x32_bf16(ah, bh, acc, 0, 0, 0);
            acc = __builtin_amdgcn_mfma_f32_16x16x32_bf16(ah, bl, acc, 0, 0, 0);
            acc = __builtin_amdgcn_mfma_f32_16x16x32_bf16(al, bh, acc, 0, 0, 0);
        }
    };

    // prologue: 2 chunks in flight
    stage(0, 0);
    stage(1, BK);

#pragma unroll 1
    for (int c = 0; c < NCHUNK - 1; ++c) {
        // wait own stage(c) loads (3 of stage(c+1) stay in flight), then sync
        asm volatile("s_waitcnt vmcnt(3)\n\ts_barrier" ::: "memory");
        __builtin_amdgcn_sched_barrier(0);
        if (c + 2 < NCHUNK) stage((c + 2) % 3, (c + 2) * BK);
        compute(c % 3);
    }
    asm volatile("s_waitcnt vmcnt(0)\n\ts_barrier" ::: "memory");
    __builtin_amdgcn_sched_barrier(0);
    compute((NCHUNK - 1) % 3);

    __syncthreads();
    // D layout (verified r4/r5): col = lane&15 (expert), row = (lane>>4)*4 + r (token)
    float* accs = reinterpret_cast<float*>(smem);   // [32][68] overlay
    const int drow = tt * 16 + (lane >> 4) * 4;
    const int dcol = et * 16 + (lane & 15);
#pragma unroll
    for (int r = 0; r < 4; ++r) accs[(drow + r) * 68 + dcol] = acc[r];
    __syncthreads();

    // epilogue: wave q handles token rows 4q..4q+3; lane = expert
    float* out_w = out;
    float* out_i = out + (size_t)T * TOPK;
#pragma unroll 1
    for (int m = 0; m < 4; ++m) {
        const int row = q * 4 + m;
        const int t = t0 + row;
        float lg = accs[row * 68 + lane];
        float v = 30.0f * tanhf(lg * (1.0f / 30.0f));
        float vcur = v, vmax0 = 0.f, my_e = 0.f, sum = 0.f, prev = 0.f;
        int   my_i = 0;
        bool  ambig = false;
#pragma unroll 1
        for (int k = 0; k < TOPK + 1; ++k) {   // ranks 1..9 with margin check
            float bv = vcur;
            int   bi = lane;
#pragma unroll
            for (int s = 32; s >= 1; s >>= 1) {
                float ov = __shfl_xor(bv, s);
                int   oi = __shfl_xor(bi, s);
                if (ov > bv || (ov == bv && oi < bi)) { bv = ov; bi = oi; }
            }
            if (k == 0) vmax0 = bv;
            else        ambig |= (prev - bv < MARGIN);
            prev = bv;
            if (k < TOPK) {
                float e = __expf(bv - vmax0);
                sum += e;
                if (lane == k) { my_e = e; my_i = bi; }
                if (lane == bi) vcur = -INFINITY;
            }
        }
        if (!ambig) {
            if (lane < TOPK) {
                out_w[(size_t)t * TOPK + lane] = my_e / sum;
                out_i[(size_t)t * TOPK + lane] = (float)my_i;
            }
        } else if (lane == 0) {
            redo_list[atomicAdd(redo_cnt, 1)] = t;
        }
    }
}

// ---------------- pass 2: exact f64 redo of ambiguous tokens ---------------
__global__ __launch_bounds__(256, 2)
void gate_redo(const float* __restrict__ X, const float* __restrict__ W,
               float* __restrict__ out,
               const int* __restrict__ redo_cnt, const int* __restrict__ redo_list,
               int T) {
    __shared__ double lgs[64];
    const int lane = threadIdx.x & 63;
    const int q    = threadIdx.x >> 6;
    const int n    = *redo_cnt;
    float* out_w = out;
    float* out_i = out + (size_t)T * TOPK;

    for (int i = blockIdx.x; i < n; i += gridDim.x) {
        const int t = redo_list[i];
        const float* xr = X + (size_t)t * HIDDEN;
#pragma unroll 1
        for (int j = 0; j < 16; ++j) {
            const int e = q * 16 + j;
            const float* wr = W + (size_t)e * HIDDEN;
            double s = 0.0;
#pragma unroll 2
            for (int k = lane * 4; k < HIDDEN; k += 256) {
                float4 wv = *reinterpret_cast<const float4*>(wr + k);
                float4 xv = *reinterpret_cast<const float4*>(xr + k);
                s = fma((double)xv.x, (double)wv.x, s);
                s = fma((double)xv.y, (double)wv.y, s);
                s = fma((double)xv.z, (double)wv.z, s);
                s = fma((double)xv.w, (double)wv.w, s);
            }
#pragma unroll
            for (int sft = 32; sft >= 1; sft >>= 1) s += __shfl_xor(s, sft);
            if (lane == 0) lgs[e] = s;
        }
        __syncthreads();
        if (q == 0) {
            double vv = 30.0 * tanh(lgs[lane] * (1.0 / 30.0));
            double dmax0 = 0.0, dmy_e = 0.0, dsum = 0.0;
            int    dmy_i = 0;
#pragma unroll 1
            for (int k = 0; k < TOPK; ++k) {
                double bv = vv;
                int    bi = lane;
#pragma unroll
                for (int s = 32; s >= 1; s >>= 1) {
                    double ov = __shfl_xor(bv, s);
                    int    oi = __shfl_xor(bi, s);
                    if (ov > bv || (ov == bv && oi < bi)) { bv = ov; bi = oi; }
                }
                if (k == 0) dmax0 = bv;
                double e = exp(bv - dmax0);
                dsum += e;
                if (lane == k) { dmy_e = e; dmy_i = bi; }
                if (lane == bi) vv = -HUGE_VAL;
            }
            if (lane < TOPK) {
                out_w[(size_t)t * TOPK + lane] = (float)(dmy_e / dsum);
                out_i[(size_t)t * TOPK + lane] = (float)dmy_i;
            }
        }
        __syncthreads();
    }
}

// ---------------- fallback (round-3 proven) if ws too small ----------------
#define F_HC 64
#define F_LDS_STRIDE 68
#define F_TPW 4
#define F_TPB 16

__global__ __launch_bounds__(256, 4)
void moe_gate_fallback(const float* __restrict__ X, const float* __restrict__ W,
                       float* __restrict__ out, int T) {
    __shared__ float wlds[NEXP * F_LDS_STRIDE];
    const int tid  = threadIdx.x;
    const int lane = tid & 63;
    const int wid  = tid >> 6;
    const int t0   = blockIdx.x * F_TPB + wid * F_TPW;
    double accd[F_TPW];
#pragma unroll
    for (int m = 0; m < F_TPW; ++m) accd[m] = 0.0;
    for (int hb = 0; hb < HIDDEN; hb += F_HC) {
        __syncthreads();
#pragma unroll
        for (int k = 0; k < 4; ++k) {
            int f = tid + k * 256, e = f >> 4, c4 = f & 15;
            const float4 wv = *reinterpret_cast<const float4*>(W + e * HIDDEN + hb + c4 * 4);
            *reinterpret_cast<float4*>(&wlds[e * F_LDS_STRIDE + c4 * 4]) = wv;
        }
        __syncthreads();
        float accf[F_TPW];
#pragma unroll
        for (int m = 0; m < F_TPW; ++m) accf[m] = 0.f;
#pragma unroll 4
        for (int h4 = 0; h4 < F_HC / 4; ++h4) {
            const float4 wv = *reinterpret_cast<const float4*>(&wlds[lane * F_LDS_STRIDE + h4 * 4]);
#pragma unroll
            for (int m = 0; m < F_TPW; ++m) {
                const float4 xv = *reinterpret_cast<const float4*>(
                    X + (size_t)(t0 + m) * HIDDEN + hb + h4 * 4);
                accf[m] = fmaf(xv.x, wv.x, accf[m]);
                accf[m] = fmaf(xv.y, wv.y, accf[m]);
                accf[m] = fmaf(xv.z, wv.z, accf[m]);
                accf[m] = fmaf(xv.w, wv.w, accf[m]);
            }
        }
#pragma unroll
        for (int m = 0; m < F_TPW; ++m) accd[m] += (double)accf[m];
    }
    float* out_w = out;
    float* out_i = out + (size_t)T * TOPK;
#pragma unroll 1
    for (int m = 0; m < F_TPW; ++m) {
        const int t = t0 + m;
        double vv = 30.0 * tanh(accd[m] * (1.0 / 30.0));
        double dmax0 = 0.0, dmy_e = 0.0, dsum = 0.0;
        int dmy_i = 0;
#pragma unroll 1
        for (int k = 0; k < TOPK; ++k) {
            double bv = vv; int bi = lane;
#pragma unroll
            for (int s = 32; s >= 1; s >>= 1) {
                double ov = __shfl_xor(bv, s);
                int    oi = __shfl_xor(bi, s);
                if (ov > bv || (ov == bv && oi < bi)) { bv = ov; bi = oi; }
            }
            if (k == 0) dmax0 = bv;
            double e = exp(bv - dmax0);
            dsum += e;
            if (lane == k) { dmy_e = e; dmy_i = bi; }
            if (lane == bi) vv = -HUGE_VAL;
        }
        if (lane < TOPK) {
            out_w[(size_t)t * TOPK + lane] = (float)(dmy_e / dsum);
            out_i[(size_t)t * TOPK + lane] = (float)dmy_i;
        }
    }
}

extern "C" void kernel_launch(void* const* d_in, const int* in_sizes, int n_in,
                              void* d_out, int out_size, void* d_ws, size_t ws_size,
                              hipStream_t stream) {
    const float* X = (const float*)d_in[0];     // [4,4096,4096] fp32
    const float* W = (const float*)d_in[1];     // [64,4096] fp32
    float* out = (float*)d_out;
    const int T = in_sizes[0] / HIDDEN;         // 16384

    if (ws_size < WS_NEED) {
        hipLaunchKernelGGL(moe_gate_fallback, dim3(T / F_TPB), dim3(256), 0, stream, X, W, out, T);
        return;
    }
    char* ws = (char*)d_ws;
    int* cnt  = (int*)ws;
    int* list = (int*)(ws + WS_LIST_OFF);
    unsigned short* Whi = (unsigned short*)(ws + WS_WHI_OFF);
    unsigned short* Wlo = (unsigned short*)(ws + WS_WLO_OFF);

    hipLaunchKernelGGL(wconv_kernel, dim3(256), dim3(256), 0, stream, W, Whi, Wlo, cnt);
    hipLaunchKernelGGL(gate_mfma, dim3(T / TPB), dim3(512), 0, stream,
                       X, Whi, Wlo, out, cnt, list, T);
    hipLaunchKernelGGL(gate_redo, dim3(256), dim3(256), 0, stream,
                       X, W, out, cnt, list, T);
}